// Round 8
// baseline (192.390 us; speedup 1.0000x reference)
//
#include <hip/hip_runtime.h>

typedef __attribute__((ext_vector_type(8))) short short8;
typedef __attribute__((ext_vector_type(8))) __bf16 bf16x8;
typedef __attribute__((ext_vector_type(4))) float f32x4;
typedef __attribute__((ext_vector_type(4))) float float4v;
typedef __attribute__((ext_vector_type(4))) unsigned short ushort4v;
typedef __attribute__((ext_vector_type(2))) unsigned uint2v;

#define AS1 __attribute__((address_space(1)))
#define AS3 __attribute__((address_space(3)))

#define BATCH 4
#define SEQ 1024
#define DM 1024
#define NH 16
#define DKH 64
#define MROWS (BATCH * SEQ) /* 4096 */
#define N3 (3 * DM)         /* 3072 */

static __device__ __forceinline__ unsigned short f2bf(float f) {
  unsigned u = __builtin_bit_cast(unsigned, f);
  u += 0x7FFFu + ((u >> 16) & 1u);
  return (unsigned short)(u >> 16);
}
static __device__ __forceinline__ float bf2f(unsigned short h) {
  return __builtin_bit_cast(float, ((unsigned)h) << 16);
}
static __device__ __forceinline__ f32x4 mfma16(short8 a, short8 b, f32x4 c) {
  return __builtin_amdgcn_mfma_f32_16x16x32_bf16(
      __builtin_bit_cast(bf16x8, a), __builtin_bit_cast(bf16x8, b), c, 0, 0, 0);
}

// ---------------- fp32 -> bf16 convert (x, Wq, Wk, Wv concat, Wo) ----------------
__global__ __launch_bounds__(256) void convert_kernel(
    const float* __restrict__ x, const float* __restrict__ wq,
    const float* __restrict__ wk, const float* __restrict__ wv,
    const float* __restrict__ wo, unsigned short* __restrict__ xb,
    unsigned short* __restrict__ wqkv, unsigned short* __restrict__ wob) {
  size_t i4 = ((size_t)blockIdx.x * 256 + threadIdx.x) * 4;
  const size_t SZX = (size_t)MROWS * DM;  // 4M
  const size_t SZW = (size_t)DM * DM;     // 1M
  const float* src;
  unsigned short* dst;
  size_t off;
  if (i4 < SZX) {
    src = x; dst = xb; off = i4;
  } else if (i4 < SZX + SZW) {
    src = wq; dst = wqkv; off = i4 - SZX;
  } else if (i4 < SZX + 2 * SZW) {
    src = wk; dst = wqkv + SZW; off = i4 - SZX - SZW;
  } else if (i4 < SZX + 3 * SZW) {
    src = wv; dst = wqkv + 2 * SZW; off = i4 - SZX - 2 * SZW;
  } else {
    src = wo; dst = wob; off = i4 - SZX - 3 * SZW;
  }
  float4v v = *(const float4v*)(src + off);
  ushort4v o;
  o.x = f2bf(v.x); o.y = f2bf(v.y); o.z = f2bf(v.z); o.w = f2bf(v.w);
  *(ushort4v*)(dst + off) = o;
}

// ---------------- bf16 GEMM: C[M][N] = A[M][K] * B[N][K]^T ----------------
// 128x128 tile, BK=64, 4 waves (2x2 of 64x64), global_load_lds + XOR swizzle.
static __device__ __forceinline__ void store_c(float* p, float v) { *p = v; }
static __device__ __forceinline__ void store_c(unsigned short* p, float v) { *p = f2bf(v); }

template <typename OutT>
__global__ __launch_bounds__(256) void gemm_bt(
    const unsigned short* __restrict__ A, const unsigned short* __restrict__ B,
    OutT* __restrict__ C, int M, int N, int K) {
  __shared__ char sA[16384];
  __shared__ char sB[16384];
  const int tid = threadIdx.x, w = tid >> 6, lane = tid & 63;
  const int g = lane >> 4, r = lane & 15;
  const int m0 = blockIdx.y * 128, n0 = blockIdx.x * 128;
  const int wm = (w >> 1) * 64, wn = (w & 1) * 64;
  f32x4 acc[4][4] = {};
  for (int k0 = 0; k0 < K; k0 += 64) {
#pragma unroll
    for (int c = 0; c < 4; ++c) {
      int p = c * 4096 + tid * 16;            // linear LDS byte pos
      int o = p ^ (((p >> 7) & 7) << 4);      // inverse-swizzled logical pos
      int row = o >> 7, colb = o & 127;
      const char* ga = (const char*)(A + (size_t)(m0 + row) * K + k0) + colb;
      const char* gb = (const char*)(B + (size_t)(n0 + row) * K + k0) + colb;
      __builtin_amdgcn_global_load_lds((const AS1 void*)ga,
                                       (AS3 void*)(sA + c * 4096 + (w << 10)), 16, 0, 0);
      __builtin_amdgcn_global_load_lds((const AS1 void*)gb,
                                       (AS3 void*)(sB + c * 4096 + (w << 10)), 16, 0, 0);
    }
    __syncthreads();
#pragma unroll
    for (int kk = 0; kk < 2; ++kk) {
      short8 af[4], bfr[4];
#pragma unroll
      for (int i = 0; i < 4; ++i) {
        int ra = wm + i * 16 + r;
        af[i] = *(const short8*)(sA + (((ra << 7) + (kk << 6) + (g << 4)) ^ ((ra & 7) << 4)));
        int rb = wn + i * 16 + r;
        bfr[i] = *(const short8*)(sB + (((rb << 7) + (kk << 6) + (g << 4)) ^ ((rb & 7) << 4)));
      }
#pragma unroll
      for (int i = 0; i < 4; ++i)
#pragma unroll
        for (int j = 0; j < 4; ++j) acc[i][j] = mfma16(af[i], bfr[j], acc[i][j]);
    }
    __syncthreads();
  }
#pragma unroll
  for (int i = 0; i < 4; ++i)
#pragma unroll
    for (int j = 0; j < 4; ++j)
#pragma unroll
      for (int jj = 0; jj < 4; ++jj) {
        int row = m0 + wm + i * 16 + g * 4 + jj;
        int col = n0 + wn + j * 16 + r;
        store_c(&C[(size_t)row * N + col], acc[i][j][jj]);
      }
}

// ---------------- RoPE on Q,K + relayout to (b,h,s,d); Q scaled by 1/8 ----------------
__global__ __launch_bounds__(256) void rope_qk(const unsigned short* __restrict__ cf,
                                               unsigned short* __restrict__ qb,
                                               unsigned short* __restrict__ kb) {
  int i = blockIdx.x * 256 + threadIdx.x;  // 2M pairs
  int k = i & 31, h = (i >> 5) & 15, s = (i >> 9) & 1023, b = i >> 19;
  float freq = __expf(-(float)k * 0.28782313662425572f);  // 10000^(-k/32)
  float ang = (float)s * freq;
  float sn, cs;
  __sincosf(ang, &sn, &cs);
  const unsigned short* src = cf + (size_t)(b * SEQ + s) * N3 + h * DKH + 2 * k;
  float qe = bf2f(src[0]), qo = bf2f(src[1]);
  float ke = bf2f(src[DM]), ko = bf2f(src[DM + 1]);
  float q0 = (qe * cs - qo * sn) * 0.125f;
  float q1 = (qe * sn + qo * cs) * 0.125f;
  float k0 = ke * cs - ko * sn;
  float k1 = ke * sn + ko * cs;
  size_t dsto = (size_t)((b * NH + h) * SEQ + s) * DKH + 2 * k;
  *(unsigned*)(qb + dsto) = (unsigned)f2bf(q0) | ((unsigned)f2bf(q1) << 16);
  *(unsigned*)(kb + dsto) = (unsigned)f2bf(k0) | ((unsigned)f2bf(k1) << 16);
}

// ---------------- V transpose: cf V slice (b,s,h,d) -> vt (b,h,d,s) ----------------
__global__ __launch_bounds__(256) void transpose_v(const unsigned short* __restrict__ cf,
                                                   unsigned short* __restrict__ vt) {
  __shared__ unsigned short tile[64][72];  // [s][d], stride 72 keeps 16B alignment
  int bh = blockIdx.y, b = bh >> 4, h = bh & 15, s0 = blockIdx.x * 64;
  int t = threadIdx.x, row = t >> 2, c0 = (t & 3) * 16;
  const unsigned short* src = cf + (size_t)(b * SEQ + s0 + row) * N3 + 2 * DM + h * DKH + c0;
  short8 v0 = *(const short8*)src;
  short8 v1 = *(const short8*)(src + 8);
  *(short8*)&tile[row][c0] = v0;
  *(short8*)&tile[row][c0 + 8] = v1;
  __syncthreads();
  unsigned short* dst = vt + ((size_t)bh * DKH + row) * SEQ + s0 + c0;
  short8 o0, o1;
#pragma unroll
  for (int j = 0; j < 8; ++j) o0[j] = (short)tile[c0 + j][row];
#pragma unroll
  for (int j = 0; j < 8; ++j) o1[j] = (short)tile[c0 + 8 + j][row];
  *(short8*)dst = o0;
  *(short8*)(dst + 8) = o1;
}

// ---------------- causal flash attention (v6: KVBLK=128, K-only staging) ----------
// grid (8, 64), 4 waves, paired q-blocks (qlo=bx, qhi=15-bx, 64 rows each).
// 128-key tiles: softmax updates/barriers halved per key. K staged in LDS
// (dbuf 2x16KB, gload_lds + XOR swizzle); V read DIRECT from global (L2-resident,
// m169: stage only when not cache-fit). Swapped-operand math as v4 (q-on-col,
// per-lane softmax). setprio(1) around MFMA clusters (T5).
__global__ __launch_bounds__(256, 2) void attn_kernel(const unsigned short* __restrict__ qb,
                                                      const unsigned short* __restrict__ kb,
                                                      const unsigned short* __restrict__ vt,
                                                      unsigned short* __restrict__ ob) {
  __shared__ char kl[2][16384];
  __shared__ unsigned short plds[4][2][2048];  // per-wave P: 16q x 128k bf16 (hi, lo)
  const int bx = blockIdx.x, bh = blockIdx.y, b = bh >> 4, h = bh & 15;
  const int qlo = bx, qhi = 15 - bx;
  const int tid = threadIdx.x, w = tid >> 6, lane = tid & 63;
  const int g = lane >> 4, r = lane & 15;
  const unsigned short* Q = qb + (size_t)bh * SEQ * DKH;
  const char* Kp = (const char*)(kb + (size_t)bh * SEQ * DKH);
  const char* Vp = (const char*)(vt + (size_t)bh * DKH * SEQ);

  // K staging: 16KB tile, 256 threads x 4 chunks x 16B; linear dest, inv-swz src
  const int pc0 = tid * 16;
  size_t ks[4];
#pragma unroll
  for (int c = 0; c < 4; ++c) {
    int p = c * 4096 + pc0;
    int o = p ^ (((p >> 7) & 7) << 4);
    ks[c] = (size_t)(o >> 7) * 128 + (o & 127);
  }

#define STAGE_K(bi, kt)                                                           \
  do {                                                                            \
    const char* kbase = Kp + (size_t)(kt) * 16384;                                \
    _Pragma("unroll") for (int c = 0; c < 4; ++c) {                               \
      __builtin_amdgcn_global_load_lds((const AS1 void*)(kbase + ks[c]),          \
                                       (AS3 void*)(kl[bi] + c * 4096 + pc0), 16,  \
                                       0, 0);                                     \
    }                                                                             \
  } while (0)

  short8 qfL0, qfL1, qfH0, qfH1;
  {
    int qrL = qlo * 64 + w * 16 + r;
    int qrH = qhi * 64 + w * 16 + r;
    qfL0 = *(const short8*)(Q + (size_t)qrL * DKH + g * 8);
    qfL1 = *(const short8*)(Q + (size_t)qrL * DKH + 32 + g * 8);
    qfH0 = *(const short8*)(Q + (size_t)qrH * DKH + g * 8);
    qfH1 = *(const short8*)(Q + (size_t)qrH * DKH + 32 + g * 8);
  }
  f32x4 oaccL[4] = {}, oaccH[4] = {};
  float mrunL = -1e30f, lrunL = 0.f, mrunH = -1e30f, lrunH = 0.f;
  const int qgH = qhi * 64 + w * 16 + r;
  const int qgL = qlo * 64 + w * 16 + r;
  char* pbH = (char*)&plds[w][0][0];
  char* pbL = (char*)&plds[w][1][0];
  const int nktH = (qhi + 2) >> 1;  // 128-key tiles for hi span
  const int nktL = (qlo + 2) >> 1;

  STAGE_K(0, 0);
  __syncthreads();

  for (int kt = 0; kt < nktH; ++kt) {
    if (kt + 1 < nktH) STAGE_K((kt + 1) & 1, kt + 1);  // prefetch next K tile
    const bool doLo = (kt < nktL);
    const char* kb_ = kl[kt & 1];
    f32x4 sh[8] = {}, sl[8] = {};
    __builtin_amdgcn_s_setprio(1);
#pragma unroll
    for (int nb = 0; nb < 8; ++nb) {
      int ra = nb * 16 + r;
      short8 kf0 = *(const short8*)(kb_ + ((ra * 128 + g * 16) ^ ((ra & 7) << 4)));
      short8 kf1 = *(const short8*)(kb_ + ((ra * 128 + 64 + g * 16) ^ ((ra & 7) << 4)));
      sh[nb] = mfma16(kf0, qfH0, sh[nb]);  // swapped: S[k][q]
      sh[nb] = mfma16(kf1, qfH1, sh[nb]);
      if (doLo) {
        sl[nb] = mfma16(kf0, qfL0, sl[nb]);
        sl[nb] = mfma16(kf1, qfL1, sl[nb]);
      }
    }
    __builtin_amdgcn_s_setprio(0);
    // diagonal masks (generic k>q test; fires only on each chain's last tile)
    if (kt == nktH - 1) {
#pragma unroll
      for (int nb = 0; nb < 8; ++nb)
#pragma unroll
        for (int j = 0; j < 4; ++j)
          if (kt * 128 + nb * 16 + g * 4 + j > qgH) sh[nb][j] = -1e30f;
    }
    if (doLo && kt == nktL - 1) {
#pragma unroll
      for (int nb = 0; nb < 8; ++nb)
#pragma unroll
        for (int j = 0; j < 4; ++j)
          if (kt * 128 + nb * 16 + g * 4 + j > qgL) sl[nb][j] = -1e30f;
    }
    // ---- softmax H (per-lane row over 32 values + 2 shfl) ----
    float sclH, sclL = 1.f;
    {
      float tm = -1e30f;
#pragma unroll
      for (int nb = 0; nb < 8; ++nb)
        tm = fmaxf(tm, fmaxf(fmaxf(sh[nb][0], sh[nb][1]), fmaxf(sh[nb][2], sh[nb][3])));
      tm = fmaxf(tm, __shfl_xor(tm, 16, 64));
      tm = fmaxf(tm, __shfl_xor(tm, 32, 64));
      float mnew = fmaxf(mrunH, tm);
      sclH = __expf(mrunH - mnew);
      mrunH = mnew;
      float ps = 0.f;
#pragma unroll
      for (int nb = 0; nb < 8; ++nb)
#pragma unroll
        for (int j = 0; j < 4; ++j) {
          float p = __expf(sh[nb][j] - mnew);
          sh[nb][j] = p;
          ps += p;
        }
      ps += __shfl_xor(ps, 16, 64);
      ps += __shfl_xor(ps, 32, 64);
      lrunH = lrunH * sclH + ps;
#pragma unroll
      for (int nb = 0; nb < 8; ++nb) {
        uint2v pk;
        pk.x = (unsigned)f2bf(sh[nb][0]) | ((unsigned)f2bf(sh[nb][1]) << 16);
        pk.y = (unsigned)f2bf(sh[nb][2]) | ((unsigned)f2bf(sh[nb][3]) << 16);
        *(uint2v*)(pbH + ((r * 256 + nb * 32 + g * 8) ^ ((r & 7) << 4))) = pk;
      }
    }
    // ---- softmax L ----
    if (doLo) {
      float tm = -1e30f;
#pragma unroll
      for (int nb = 0; nb < 8; ++nb)
        tm = fmaxf(tm, fmaxf(fmaxf(sl[nb][0], sl[nb][1]), fmaxf(sl[nb][2], sl[nb][3])));
      tm = fmaxf(tm, __shfl_xor(tm, 16, 64));
      tm = fmaxf(tm, __shfl_xor(tm, 32, 64));
      float mnew = fmaxf(mrunL, tm);
      sclL = __expf(mrunL - mnew);
      mrunL = mnew;
      float ps = 0.f;
#pragma unroll
      for (int nb = 0; nb < 8; ++nb)
#pragma unroll
        for (int j = 0; j < 4; ++j) {
          float p = __expf(sl[nb][j] - mnew);
          sl[nb][j] = p;
          ps += p;
        }
      ps += __shfl_xor(ps, 16, 64);
      ps += __shfl_xor(ps, 32, 64);
      lrunL = lrunL * sclL + ps;
#pragma unroll
      for (int nb = 0; nb < 8; ++nb) {
        uint2v pk;
        pk.x = (unsigned)f2bf(sl[nb][0]) | ((unsigned)f2bf(sl[nb][1]) << 16);
        pk.y = (unsigned)f2bf(sl[nb][2]) | ((unsigned)f2bf(sl[nb][3]) << 16);
        *(uint2v*)(pbL + ((r * 256 + nb * 32 + g * 8) ^ ((r & 7) << 4))) = pk;
      }
    }
    // rescale O accumulators (per-lane scalar)
#pragma unroll
    for (int db = 0; db < 4; ++db) {
      f32x4 t = oaccH[db];
      t[0] *= sclH; t[1] *= sclH; t[2] *= sclH; t[3] *= sclH;
      oaccH[db] = t;
      if (doLo) {
        f32x4 u = oaccL[db];
        u[0] *= sclL; u[1] *= sclL; u[2] *= sclL; u[3] *= sclL;
        oaccL[db] = u;
      }
    }
    // P write -> read is same-wave only
    asm volatile("s_waitcnt lgkmcnt(0)" ::: "memory");
    __builtin_amdgcn_sched_barrier(0);
    short8 pfH[4], pfL[4];
#pragma unroll
    for (int kss = 0; kss < 4; ++kss) {
      pfH[kss] = *(const short8*)(pbH + ((r * 256 + kss * 64 + g * 16) ^ ((r & 7) << 4)));
      if (doLo)
        pfL[kss] = *(const short8*)(pbL + ((r * 256 + kss * 64 + g * 16) ^ ((r & 7) << 4)));
    }
    __builtin_amdgcn_s_setprio(1);
#pragma unroll
    for (int db = 0; db < 4; ++db) {
      const char* vrow = Vp + (size_t)(db * 16 + r) * 2048 + (size_t)kt * 256 + g * 16;
#pragma unroll
      for (int kss = 0; kss < 4; ++kss) {
        short8 vf = *(const short8*)(vrow + kss * 64);  // V^T direct from L2
        oaccH[db] = mfma16(vf, pfH[kss], oaccH[db]);    // swapped: O[d][q]
        if (doLo) oaccL[db] = mfma16(vf, pfL[kss], oaccL[db]);
      }
    }
    __builtin_amdgcn_s_setprio(0);
    __syncthreads();  // staging drained + all waves done with K buffer
  }
  // epilogue: lane holds O[d=db*16+g*4+j][q=own row]; pack 4 bf16 -> 8B stores
  {
    float invH = 1.f / lrunH;
    unsigned short* orH = ob + (size_t)(b * SEQ + qgH) * DM + h * DKH;
#pragma unroll
    for (int db = 0; db < 4; ++db) {
      uint2v pk;
      pk.x = (unsigned)f2bf(oaccH[db][0] * invH) | ((unsigned)f2bf(oaccH[db][1] * invH) << 16);
      pk.y = (unsigned)f2bf(oaccH[db][2] * invH) | ((unsigned)f2bf(oaccH[db][3] * invH) << 16);
      *(uint2v*)(orH + db * 16 + g * 4) = pk;
    }
    float invL = 1.f / lrunL;
    unsigned short* orL = ob + (size_t)(b * SEQ + qgL) * DM + h * DKH;
#pragma unroll
    for (int db = 0; db < 4; ++db) {
      uint2v pk;
      pk.x = (unsigned)f2bf(oaccL[db][0] * invL) | ((unsigned)f2bf(oaccL[db][1] * invL) << 16);
      pk.y = (unsigned)f2bf(oaccL[db][2] * invL) | ((unsigned)f2bf(oaccL[db][3] * invL) << 16);
      *(uint2v*)(orL + db * 16 + g * 4) = pk;
    }
  }
#undef STAGE_K
}

extern "C" void kernel_launch(void* const* d_in, const int* in_sizes, int n_in,
                              void* d_out, int out_size, void* d_ws, size_t ws_size,
                              hipStream_t stream) {
  const float* x = (const float*)d_in[0];
  // d_in[1] = token_positions (reference ignores it; positions == arange(S))
  const float* wq = (const float*)d_in[2];
  const float* wk = (const float*)d_in[3];
  const float* wv = (const float*)d_in[4];
  const float* wo = (const float*)d_in[5];
  char* ws = (char*)d_ws;
  unsigned short* xb = (unsigned short*)(ws);                  // 8 MiB
  unsigned short* wqkv = (unsigned short*)(ws + (8u << 20));   // 6 MiB [Wq;Wk;Wv][3072][1024]
  unsigned short* wob = (unsigned short*)(ws + (14u << 20));   // 2 MiB
  unsigned short* cf = (unsigned short*)(ws + (16u << 20));    // 24 MiB QKV gemm out (b,s,3072)
  unsigned short* qbuf = (unsigned short*)(ws + (40u << 20));  // 8 MiB (bh,s,d)
  unsigned short* kbuf = (unsigned short*)(ws + (48u << 20));  // 8 MiB (bh,s,d)
  unsigned short* vtb = (unsigned short*)(ws + (56u << 20));   // 8 MiB (bh,d,s)
  unsigned short* obuf = (unsigned short*)(ws + (64u << 20));  // 8 MiB (b,s,e)
  float* out = (float*)d_out;

  convert_kernel<<<8192, 256, 0, stream>>>(x, wq, wk, wv, wo, xb, wqkv, wob);
  gemm_bt<unsigned short><<<dim3(24, 32), 256, 0, stream>>>(xb, wqkv, cf, MROWS, N3, DM);
  rope_qk<<<8192, 256, 0, stream>>>(cf, qbuf, kbuf);
  transpose_v<<<dim3(16, 64), 256, 0, stream>>>(cf, vtb);
  attn_kernel<<<dim3(8, 64), 256, 0, stream>>>(qbuf, kbuf, vtb, obuf);
  gemm_bt<float><<<dim3(8, 32), 256, 0, stream>>>(obuf, wob, out, MROWS, DM, DM);
}

// Round 9
// 183.634 us; speedup vs baseline: 1.0477x; 1.0477x over previous
//
#include <hip/hip_runtime.h>

typedef __attribute__((ext_vector_type(8))) short short8;
typedef __attribute__((ext_vector_type(8))) __bf16 bf16x8;
typedef __attribute__((ext_vector_type(4))) float f32x4;
typedef __attribute__((ext_vector_type(4))) float float4v;
typedef __attribute__((ext_vector_type(4))) unsigned short ushort4v;
typedef __attribute__((ext_vector_type(2))) unsigned uint2v;

#define AS1 __attribute__((address_space(1)))
#define AS3 __attribute__((address_space(3)))

#define BATCH 4
#define SEQ 1024
#define DM 1024
#define NH 16
#define DKH 64
#define MROWS (BATCH * SEQ) /* 4096 */
#define N3 (3 * DM)         /* 3072 */

static __device__ __forceinline__ unsigned short f2bf(float f) {
  unsigned u = __builtin_bit_cast(unsigned, f);
  u += 0x7FFFu + ((u >> 16) & 1u);
  return (unsigned short)(u >> 16);
}
static __device__ __forceinline__ float bf2f(unsigned short h) {
  return __builtin_bit_cast(float, ((unsigned)h) << 16);
}
static __device__ __forceinline__ f32x4 mfma16(short8 a, short8 b, f32x4 c) {
  return __builtin_amdgcn_mfma_f32_16x16x32_bf16(
      __builtin_bit_cast(bf16x8, a), __builtin_bit_cast(bf16x8, b), c, 0, 0, 0);
}

// ---------------- fp32 -> bf16 convert (x, Wq, Wk, Wv concat, Wo) ----------------
__global__ __launch_bounds__(256) void convert_kernel(
    const float* __restrict__ x, const float* __restrict__ wq,
    const float* __restrict__ wk, const float* __restrict__ wv,
    const float* __restrict__ wo, unsigned short* __restrict__ xb,
    unsigned short* __restrict__ wqkv, unsigned short* __restrict__ wob) {
  size_t i4 = ((size_t)blockIdx.x * 256 + threadIdx.x) * 4;
  const size_t SZX = (size_t)MROWS * DM;  // 4M
  const size_t SZW = (size_t)DM * DM;     // 1M
  const float* src;
  unsigned short* dst;
  size_t off;
  if (i4 < SZX) {
    src = x; dst = xb; off = i4;
  } else if (i4 < SZX + SZW) {
    src = wq; dst = wqkv; off = i4 - SZX;
  } else if (i4 < SZX + 2 * SZW) {
    src = wk; dst = wqkv + SZW; off = i4 - SZX - SZW;
  } else if (i4 < SZX + 3 * SZW) {
    src = wv; dst = wqkv + 2 * SZW; off = i4 - SZX - 2 * SZW;
  } else {
    src = wo; dst = wob; off = i4 - SZX - 3 * SZW;
  }
  float4v v = *(const float4v*)(src + off);
  ushort4v o;
  o.x = f2bf(v.x); o.y = f2bf(v.y); o.z = f2bf(v.z); o.w = f2bf(v.w);
  *(ushort4v*)(dst + off) = o;
}

// ---------------- bf16 GEMM: C[M][N] = A[M][K] * B[N][K]^T ----------------
// 128x128 tile, BK=64, 4 waves (2x2 of 64x64), global_load_lds + XOR swizzle.
static __device__ __forceinline__ void store_c(float* p, float v) { *p = v; }
static __device__ __forceinline__ void store_c(unsigned short* p, float v) { *p = f2bf(v); }

template <typename OutT>
__global__ __launch_bounds__(256) void gemm_bt(
    const unsigned short* __restrict__ A, const unsigned short* __restrict__ B,
    OutT* __restrict__ C, int M, int N, int K) {
  __shared__ char sA[16384];
  __shared__ char sB[16384];
  const int tid = threadIdx.x, w = tid >> 6, lane = tid & 63;
  const int g = lane >> 4, r = lane & 15;
  const int m0 = blockIdx.y * 128, n0 = blockIdx.x * 128;
  const int wm = (w >> 1) * 64, wn = (w & 1) * 64;
  f32x4 acc[4][4] = {};
  for (int k0 = 0; k0 < K; k0 += 64) {
#pragma unroll
    for (int c = 0; c < 4; ++c) {
      int p = c * 4096 + tid * 16;            // linear LDS byte pos
      int o = p ^ (((p >> 7) & 7) << 4);      // inverse-swizzled logical pos
      int row = o >> 7, colb = o & 127;
      const char* ga = (const char*)(A + (size_t)(m0 + row) * K + k0) + colb;
      const char* gb = (const char*)(B + (size_t)(n0 + row) * K + k0) + colb;
      __builtin_amdgcn_global_load_lds((const AS1 void*)ga,
                                       (AS3 void*)(sA + c * 4096 + (w << 10)), 16, 0, 0);
      __builtin_amdgcn_global_load_lds((const AS1 void*)gb,
                                       (AS3 void*)(sB + c * 4096 + (w << 10)), 16, 0, 0);
    }
    __syncthreads();
#pragma unroll
    for (int kk = 0; kk < 2; ++kk) {
      short8 af[4], bfr[4];
#pragma unroll
      for (int i = 0; i < 4; ++i) {
        int ra = wm + i * 16 + r;
        af[i] = *(const short8*)(sA + (((ra << 7) + (kk << 6) + (g << 4)) ^ ((ra & 7) << 4)));
        int rb = wn + i * 16 + r;
        bfr[i] = *(const short8*)(sB + (((rb << 7) + (kk << 6) + (g << 4)) ^ ((rb & 7) << 4)));
      }
#pragma unroll
      for (int i = 0; i < 4; ++i)
#pragma unroll
        for (int j = 0; j < 4; ++j) acc[i][j] = mfma16(af[i], bfr[j], acc[i][j]);
    }
    __syncthreads();
  }
#pragma unroll
  for (int i = 0; i < 4; ++i)
#pragma unroll
    for (int j = 0; j < 4; ++j)
#pragma unroll
      for (int jj = 0; jj < 4; ++jj) {
        int row = m0 + wm + i * 16 + g * 4 + jj;
        int col = n0 + wn + j * 16 + r;
        store_c(&C[(size_t)row * N + col], acc[i][j][jj]);
      }
}

// ---------------- RoPE on Q,K + relayout to (b,h,s,d); Q scaled by 1/8 ----------------
__global__ __launch_bounds__(256) void rope_qk(const unsigned short* __restrict__ cf,
                                               unsigned short* __restrict__ qb,
                                               unsigned short* __restrict__ kb) {
  int i = blockIdx.x * 256 + threadIdx.x;  // 2M pairs
  int k = i & 31, h = (i >> 5) & 15, s = (i >> 9) & 1023, b = i >> 19;
  float freq = __expf(-(float)k * 0.28782313662425572f);  // 10000^(-k/32)
  float ang = (float)s * freq;
  float sn, cs;
  __sincosf(ang, &sn, &cs);
  const unsigned short* src = cf + (size_t)(b * SEQ + s) * N3 + h * DKH + 2 * k;
  float qe = bf2f(src[0]), qo = bf2f(src[1]);
  float ke = bf2f(src[DM]), ko = bf2f(src[DM + 1]);
  float q0 = (qe * cs - qo * sn) * 0.125f;
  float q1 = (qe * sn + qo * cs) * 0.125f;
  float k0 = ke * cs - ko * sn;
  float k1 = ke * sn + ko * cs;
  size_t dsto = (size_t)((b * NH + h) * SEQ + s) * DKH + 2 * k;
  *(unsigned*)(qb + dsto) = (unsigned)f2bf(q0) | ((unsigned)f2bf(q1) << 16);
  *(unsigned*)(kb + dsto) = (unsigned)f2bf(k0) | ((unsigned)f2bf(k1) << 16);
}

// ---------------- V transpose: cf V slice (b,s,h,d) -> vt (b,h,d,s) ----------------
__global__ __launch_bounds__(256) void transpose_v(const unsigned short* __restrict__ cf,
                                                   unsigned short* __restrict__ vt) {
  __shared__ unsigned short tile[64][72];  // [s][d], stride 72 keeps 16B alignment
  int bh = blockIdx.y, b = bh >> 4, h = bh & 15, s0 = blockIdx.x * 64;
  int t = threadIdx.x, row = t >> 2, c0 = (t & 3) * 16;
  const unsigned short* src = cf + (size_t)(b * SEQ + s0 + row) * N3 + 2 * DM + h * DKH + c0;
  short8 v0 = *(const short8*)src;
  short8 v1 = *(const short8*)(src + 8);
  *(short8*)&tile[row][c0] = v0;
  *(short8*)&tile[row][c0 + 8] = v1;
  __syncthreads();
  unsigned short* dst = vt + ((size_t)bh * DKH + row) * SEQ + s0 + c0;
  short8 o0, o1;
#pragma unroll
  for (int j = 0; j < 8; ++j) o0[j] = (short)tile[c0 + j][row];
#pragma unroll
  for (int j = 0; j < 8; ++j) o1[j] = (short)tile[c0 + 8 + j][row];
  *(short8*)dst = o0;
  *(short8*)(dst + 8) = o1;
}

// ---------------- causal flash attention (v6b: KVBLK=128, K-only staging) ----------
// grid (8, 64), 4 waves, paired q-blocks (qlo=bx, qhi=15-bx, 64 rows each).
// 128-key tiles: softmax updates/barriers halved per key. K staged in LDS
// (dbuf 2x16KB, gload_lds + XOR swizzle); V read DIRECT from global (L2-resident).
// Swapped-operand math as v4 (q-on-col, per-lane softmax). setprio around MFMA.
// NOTE: NO min-waves launch bound — v6 with (256,2) capped VGPR at 128 and
// spilled the S-tiles to scratch (WRITE_SIZE 8->82MB, 3x slowdown).
__global__ __launch_bounds__(256) void attn_kernel(const unsigned short* __restrict__ qb,
                                                   const unsigned short* __restrict__ kb,
                                                   const unsigned short* __restrict__ vt,
                                                   unsigned short* __restrict__ ob) {
  __shared__ char kl[2][16384];
  __shared__ unsigned short plds[4][2][2048];  // per-wave P: 16q x 128k bf16 (hi, lo)
  const int bx = blockIdx.x, bh = blockIdx.y, b = bh >> 4, h = bh & 15;
  const int qlo = bx, qhi = 15 - bx;
  const int tid = threadIdx.x, w = tid >> 6, lane = tid & 63;
  const int g = lane >> 4, r = lane & 15;
  const unsigned short* Q = qb + (size_t)bh * SEQ * DKH;
  const char* Kp = (const char*)(kb + (size_t)bh * SEQ * DKH);
  const char* Vp = (const char*)(vt + (size_t)bh * DKH * SEQ);

  // K staging: 16KB tile, 256 threads x 4 chunks x 16B; linear dest, inv-swz src
  const int pc0 = tid * 16;
  size_t ks[4];
#pragma unroll
  for (int c = 0; c < 4; ++c) {
    int p = c * 4096 + pc0;
    int o = p ^ (((p >> 7) & 7) << 4);
    ks[c] = (size_t)(o >> 7) * 128 + (o & 127);
  }

#define STAGE_K(bi, kt)                                                           \
  do {                                                                            \
    const char* kbase = Kp + (size_t)(kt) * 16384;                                \
    _Pragma("unroll") for (int c = 0; c < 4; ++c) {                               \
      __builtin_amdgcn_global_load_lds((const AS1 void*)(kbase + ks[c]),          \
                                       (AS3 void*)(kl[bi] + c * 4096 + pc0), 16,  \
                                       0, 0);                                     \
    }                                                                             \
  } while (0)

  short8 qfL0, qfL1, qfH0, qfH1;
  {
    int qrL = qlo * 64 + w * 16 + r;
    int qrH = qhi * 64 + w * 16 + r;
    qfL0 = *(const short8*)(Q + (size_t)qrL * DKH + g * 8);
    qfL1 = *(const short8*)(Q + (size_t)qrL * DKH + 32 + g * 8);
    qfH0 = *(const short8*)(Q + (size_t)qrH * DKH + g * 8);
    qfH1 = *(const short8*)(Q + (size_t)qrH * DKH + 32 + g * 8);
  }
  f32x4 oaccL[4] = {}, oaccH[4] = {};
  float mrunL = -1e30f, lrunL = 0.f, mrunH = -1e30f, lrunH = 0.f;
  const int qgH = qhi * 64 + w * 16 + r;
  const int qgL = qlo * 64 + w * 16 + r;
  char* pbH = (char*)&plds[w][0][0];
  char* pbL = (char*)&plds[w][1][0];
  const int nktH = (qhi + 2) >> 1;  // 128-key tiles for hi span
  const int nktL = (qlo + 2) >> 1;

  STAGE_K(0, 0);
  __syncthreads();

  for (int kt = 0; kt < nktH; ++kt) {
    if (kt + 1 < nktH) STAGE_K((kt + 1) & 1, kt + 1);  // prefetch next K tile
    const bool doLo = (kt < nktL);
    const char* kb_ = kl[kt & 1];
    f32x4 sh[8] = {}, sl[8] = {};
    __builtin_amdgcn_s_setprio(1);
#pragma unroll
    for (int nb = 0; nb < 8; ++nb) {
      int ra = nb * 16 + r;
      short8 kf0 = *(const short8*)(kb_ + ((ra * 128 + g * 16) ^ ((ra & 7) << 4)));
      short8 kf1 = *(const short8*)(kb_ + ((ra * 128 + 64 + g * 16) ^ ((ra & 7) << 4)));
      sh[nb] = mfma16(kf0, qfH0, sh[nb]);  // swapped: S[k][q]
      sh[nb] = mfma16(kf1, qfH1, sh[nb]);
      if (doLo) {
        sl[nb] = mfma16(kf0, qfL0, sl[nb]);
        sl[nb] = mfma16(kf1, qfL1, sl[nb]);
      }
    }
    __builtin_amdgcn_s_setprio(0);
    // diagonal masks (generic k>q test; fires only on each chain's last tile)
    if (kt == nktH - 1) {
#pragma unroll
      for (int nb = 0; nb < 8; ++nb)
#pragma unroll
        for (int j = 0; j < 4; ++j)
          if (kt * 128 + nb * 16 + g * 4 + j > qgH) sh[nb][j] = -1e30f;
    }
    if (doLo && kt == nktL - 1) {
#pragma unroll
      for (int nb = 0; nb < 8; ++nb)
#pragma unroll
        for (int j = 0; j < 4; ++j)
          if (kt * 128 + nb * 16 + g * 4 + j > qgL) sl[nb][j] = -1e30f;
    }
    // ---- softmax H (per-lane row over 32 values + 2 shfl) ----
    float sclH, sclL = 1.f;
    {
      float tm = -1e30f;
#pragma unroll
      for (int nb = 0; nb < 8; ++nb)
        tm = fmaxf(tm, fmaxf(fmaxf(sh[nb][0], sh[nb][1]), fmaxf(sh[nb][2], sh[nb][3])));
      tm = fmaxf(tm, __shfl_xor(tm, 16, 64));
      tm = fmaxf(tm, __shfl_xor(tm, 32, 64));
      float mnew = fmaxf(mrunH, tm);
      sclH = __expf(mrunH - mnew);
      mrunH = mnew;
      float ps = 0.f;
#pragma unroll
      for (int nb = 0; nb < 8; ++nb)
#pragma unroll
        for (int j = 0; j < 4; ++j) {
          float p = __expf(sh[nb][j] - mnew);
          sh[nb][j] = p;
          ps += p;
        }
      ps += __shfl_xor(ps, 16, 64);
      ps += __shfl_xor(ps, 32, 64);
      lrunH = lrunH * sclH + ps;
#pragma unroll
      for (int nb = 0; nb < 8; ++nb) {
        uint2v pk;
        pk.x = (unsigned)f2bf(sh[nb][0]) | ((unsigned)f2bf(sh[nb][1]) << 16);
        pk.y = (unsigned)f2bf(sh[nb][2]) | ((unsigned)f2bf(sh[nb][3]) << 16);
        *(uint2v*)(pbH + ((r * 256 + nb * 32 + g * 8) ^ ((r & 7) << 4))) = pk;
      }
    }
    // ---- softmax L ----
    if (doLo) {
      float tm = -1e30f;
#pragma unroll
      for (int nb = 0; nb < 8; ++nb)
        tm = fmaxf(tm, fmaxf(fmaxf(sl[nb][0], sl[nb][1]), fmaxf(sl[nb][2], sl[nb][3])));
      tm = fmaxf(tm, __shfl_xor(tm, 16, 64));
      tm = fmaxf(tm, __shfl_xor(tm, 32, 64));
      float mnew = fmaxf(mrunL, tm);
      sclL = __expf(mrunL - mnew);
      mrunL = mnew;
      float ps = 0.f;
#pragma unroll
      for (int nb = 0; nb < 8; ++nb)
#pragma unroll
        for (int j = 0; j < 4; ++j) {
          float p = __expf(sl[nb][j] - mnew);
          sl[nb][j] = p;
          ps += p;
        }
      ps += __shfl_xor(ps, 16, 64);
      ps += __shfl_xor(ps, 32, 64);
      lrunL = lrunL * sclL + ps;
#pragma unroll
      for (int nb = 0; nb < 8; ++nb) {
        uint2v pk;
        pk.x = (unsigned)f2bf(sl[nb][0]) | ((unsigned)f2bf(sl[nb][1]) << 16);
        pk.y = (unsigned)f2bf(sl[nb][2]) | ((unsigned)f2bf(sl[nb][3]) << 16);
        *(uint2v*)(pbL + ((r * 256 + nb * 32 + g * 8) ^ ((r & 7) << 4))) = pk;
      }
    }
    // rescale O accumulators (per-lane scalar)
#pragma unroll
    for (int db = 0; db < 4; ++db) {
      f32x4 t = oaccH[db];
      t[0] *= sclH; t[1] *= sclH; t[2] *= sclH; t[3] *= sclH;
      oaccH[db] = t;
      if (doLo) {
        f32x4 u = oaccL[db];
        u[0] *= sclL; u[1] *= sclL; u[2] *= sclL; u[3] *= sclL;
        oaccL[db] = u;
      }
    }
    // P write -> read is same-wave only
    asm volatile("s_waitcnt lgkmcnt(0)" ::: "memory");
    __builtin_amdgcn_sched_barrier(0);
    short8 pfH[4], pfL[4];
#pragma unroll
    for (int kss = 0; kss < 4; ++kss) {
      pfH[kss] = *(const short8*)(pbH + ((r * 256 + kss * 64 + g * 16) ^ ((r & 7) << 4)));
      if (doLo)
        pfL[kss] = *(const short8*)(pbL + ((r * 256 + kss * 64 + g * 16) ^ ((r & 7) << 4)));
    }
    __builtin_amdgcn_s_setprio(1);
#pragma unroll
    for (int db = 0; db < 4; ++db) {
      const char* vrow = Vp + (size_t)(db * 16 + r) * 2048 + (size_t)kt * 256 + g * 16;
#pragma unroll
      for (int kss = 0; kss < 4; ++kss) {
        short8 vf = *(const short8*)(vrow + kss * 64);  // V^T direct from L2
        oaccH[db] = mfma16(vf, pfH[kss], oaccH[db]);    // swapped: O[d][q]
        if (doLo) oaccL[db] = mfma16(vf, pfL[kss], oaccL[db]);
      }
    }
    __builtin_amdgcn_s_setprio(0);
    __syncthreads();  // staging drained + all waves done with K buffer
  }
  // epilogue: lane holds O[d=db*16+g*4+j][q=own row]; pack 4 bf16 -> 8B stores
  {
    float invH = 1.f / lrunH;
    unsigned short* orH = ob + (size_t)(b * SEQ + qgH) * DM + h * DKH;
#pragma unroll
    for (int db = 0; db < 4; ++db) {
      uint2v pk;
      pk.x = (unsigned)f2bf(oaccH[db][0] * invH) | ((unsigned)f2bf(oaccH[db][1] * invH) << 16);
      pk.y = (unsigned)f2bf(oaccH[db][2] * invH) | ((unsigned)f2bf(oaccH[db][3] * invH) << 16);
      *(uint2v*)(orH + db * 16 + g * 4) = pk;
    }
    float invL = 1.f / lrunL;
    unsigned short* orL = ob + (size_t)(b * SEQ + qgL) * DM + h * DKH;
#pragma unroll
    for (int db = 0; db < 4; ++db) {
      uint2v pk;
      pk.x = (unsigned)f2bf(oaccL[db][0] * invL) | ((unsigned)f2bf(oaccL[db][1] * invL) << 16);
      pk.y = (unsigned)f2bf(oaccL[db][2] * invL) | ((unsigned)f2bf(oaccL[db][3] * invL) << 16);
      *(uint2v*)(orL + db * 16 + g * 4) = pk;
    }
  }
#undef STAGE_K
}

extern "C" void kernel_launch(void* const* d_in, const int* in_sizes, int n_in,
                              void* d_out, int out_size, void* d_ws, size_t ws_size,
                              hipStream_t stream) {
  const float* x = (const float*)d_in[0];
  // d_in[1] = token_positions (reference ignores it; positions == arange(S))
  const float* wq = (const float*)d_in[2];
  const float* wk = (const float*)d_in[3];
  const float* wv = (const float*)d_in[4];
  const float* wo = (const float*)d_in[5];
  char* ws = (char*)d_ws;
  unsigned short* xb = (unsigned short*)(ws);                  // 8 MiB
  unsigned short* wqkv = (unsigned short*)(ws + (8u << 20));   // 6 MiB [Wq;Wk;Wv][3072][1024]
  unsigned short* wob = (unsigned short*)(ws + (14u << 20));   // 2 MiB
  unsigned short* cf = (unsigned short*)(ws + (16u << 20));    // 24 MiB QKV gemm out (b,s,3072)
  unsigned short* qbuf = (unsigned short*)(ws + (40u << 20));  // 8 MiB (bh,s,d)
  unsigned short* kbuf = (unsigned short*)(ws + (48u << 20));  // 8 MiB (bh,s,d)
  unsigned short* vtb = (unsigned short*)(ws + (56u << 20));   // 8 MiB (bh,d,s)
  unsigned short* obuf = (unsigned short*)(ws + (64u << 20));  // 8 MiB (b,s,e)
  float* out = (float*)d_out;

  convert_kernel<<<8192, 256, 0, stream>>>(x, wq, wk, wv, wo, xb, wqkv, wob);
  gemm_bt<unsigned short><<<dim3(24, 32), 256, 0, stream>>>(xb, wqkv, cf, MROWS, N3, DM);
  rope_qk<<<8192, 256, 0, stream>>>(cf, qbuf, kbuf);
  transpose_v<<<dim3(16, 64), 256, 0, stream>>>(cf, vtb);
  attn_kernel<<<dim3(8, 64), 256, 0, stream>>>(qbuf, kbuf, vtb, obuf);
  gemm_bt<float><<<dim3(8, 32), 256, 0, stream>>>(obuf, wob, out, MROWS, DM, DM);
}

// Round 10
// 113.115 us; speedup vs baseline: 1.7008x; 1.6234x over previous
//
#include <hip/hip_runtime.h>

typedef __attribute__((ext_vector_type(8))) short short8;
typedef __attribute__((ext_vector_type(8))) __bf16 bf16x8;
typedef __attribute__((ext_vector_type(4))) float f32x4;
typedef __attribute__((ext_vector_type(4))) float float4v;
typedef __attribute__((ext_vector_type(4))) unsigned short ushort4v;
typedef __attribute__((ext_vector_type(2))) unsigned uint2v;

#define AS1 __attribute__((address_space(1)))
#define AS3 __attribute__((address_space(3)))

#define BATCH 4
#define SEQ 1024
#define DM 1024
#define NH 16
#define DKH 64
#define MROWS (BATCH * SEQ) /* 4096 */
#define N3 (3 * DM)         /* 3072 */

static __device__ __forceinline__ unsigned short f2bf(float f) {
  unsigned u = __builtin_bit_cast(unsigned, f);
  u += 0x7FFFu + ((u >> 16) & 1u);
  return (unsigned short)(u >> 16);
}
static __device__ __forceinline__ float bf2f(unsigned short h) {
  return __builtin_bit_cast(float, ((unsigned)h) << 16);
}
// HW packed f32x2 -> bf16x2 (RTNE), replaces ~10 int-ops of manual round+pack
static __device__ __forceinline__ unsigned cvt_pk_bf16(float lo, float hi) {
  unsigned r;
  asm("v_cvt_pk_bf16_f32 %0, %1, %2" : "=v"(r) : "v"(lo), "v"(hi));
  return r;
}
static __device__ __forceinline__ f32x4 mfma16(short8 a, short8 b, f32x4 c) {
  return __builtin_amdgcn_mfma_f32_16x16x32_bf16(
      __builtin_bit_cast(bf16x8, a), __builtin_bit_cast(bf16x8, b), c, 0, 0, 0);
}

// ---------------- fp32 -> bf16 convert (x, Wq, Wk, Wv concat, Wo) ----------------
__global__ __launch_bounds__(256) void convert_kernel(
    const float* __restrict__ x, const float* __restrict__ wq,
    const float* __restrict__ wk, const float* __restrict__ wv,
    const float* __restrict__ wo, unsigned short* __restrict__ xb,
    unsigned short* __restrict__ wqkv, unsigned short* __restrict__ wob) {
  size_t i4 = ((size_t)blockIdx.x * 256 + threadIdx.x) * 4;
  const size_t SZX = (size_t)MROWS * DM;  // 4M
  const size_t SZW = (size_t)DM * DM;     // 1M
  const float* src;
  unsigned short* dst;
  size_t off;
  if (i4 < SZX) {
    src = x; dst = xb; off = i4;
  } else if (i4 < SZX + SZW) {
    src = wq; dst = wqkv; off = i4 - SZX;
  } else if (i4 < SZX + 2 * SZW) {
    src = wk; dst = wqkv + SZW; off = i4 - SZX - SZW;
  } else if (i4 < SZX + 3 * SZW) {
    src = wv; dst = wqkv + 2 * SZW; off = i4 - SZX - 2 * SZW;
  } else {
    src = wo; dst = wob; off = i4 - SZX - 3 * SZW;
  }
  float4v v = *(const float4v*)(src + off);
  uint2v o;
  o.x = cvt_pk_bf16(v.x, v.y);
  o.y = cvt_pk_bf16(v.z, v.w);
  *(uint2v*)(dst + off) = o;
}

// ---------------- bf16 GEMM: C[M][N] = A[M][K] * B[N][K]^T ----------------
// 128x128 tile, BK=64, 4 waves (2x2 of 64x64), global_load_lds + XOR swizzle.
static __device__ __forceinline__ void store_c(float* p, float v) { *p = v; }
static __device__ __forceinline__ void store_c(unsigned short* p, float v) { *p = f2bf(v); }

template <typename OutT>
__global__ __launch_bounds__(256) void gemm_bt(
    const unsigned short* __restrict__ A, const unsigned short* __restrict__ B,
    OutT* __restrict__ C, int M, int N, int K) {
  __shared__ char sA[16384];
  __shared__ char sB[16384];
  const int tid = threadIdx.x, w = tid >> 6, lane = tid & 63;
  const int g = lane >> 4, r = lane & 15;
  const int m0 = blockIdx.y * 128, n0 = blockIdx.x * 128;
  const int wm = (w >> 1) * 64, wn = (w & 1) * 64;
  f32x4 acc[4][4] = {};
  for (int k0 = 0; k0 < K; k0 += 64) {
#pragma unroll
    for (int c = 0; c < 4; ++c) {
      int p = c * 4096 + tid * 16;            // linear LDS byte pos
      int o = p ^ (((p >> 7) & 7) << 4);      // inverse-swizzled logical pos
      int row = o >> 7, colb = o & 127;
      const char* ga = (const char*)(A + (size_t)(m0 + row) * K + k0) + colb;
      const char* gb = (const char*)(B + (size_t)(n0 + row) * K + k0) + colb;
      __builtin_amdgcn_global_load_lds((const AS1 void*)ga,
                                       (AS3 void*)(sA + c * 4096 + (w << 10)), 16, 0, 0);
      __builtin_amdgcn_global_load_lds((const AS1 void*)gb,
                                       (AS3 void*)(sB + c * 4096 + (w << 10)), 16, 0, 0);
    }
    __syncthreads();
#pragma unroll
    for (int kk = 0; kk < 2; ++kk) {
      short8 af[4], bfr[4];
#pragma unroll
      for (int i = 0; i < 4; ++i) {
        int ra = wm + i * 16 + r;
        af[i] = *(const short8*)(sA + (((ra << 7) + (kk << 6) + (g << 4)) ^ ((ra & 7) << 4)));
        int rb = wn + i * 16 + r;
        bfr[i] = *(const short8*)(sB + (((rb << 7) + (kk << 6) + (g << 4)) ^ ((rb & 7) << 4)));
      }
#pragma unroll
      for (int i = 0; i < 4; ++i)
#pragma unroll
        for (int j = 0; j < 4; ++j) acc[i][j] = mfma16(af[i], bfr[j], acc[i][j]);
    }
    __syncthreads();
  }
#pragma unroll
  for (int i = 0; i < 4; ++i)
#pragma unroll
    for (int j = 0; j < 4; ++j)
#pragma unroll
      for (int jj = 0; jj < 4; ++jj) {
        int row = m0 + wm + i * 16 + g * 4 + jj;
        int col = n0 + wn + j * 16 + r;
        store_c(&C[(size_t)row * N + col], acc[i][j][jj]);
      }
}

// ---------------- fused RoPE(Q,K) + V-transpose pre-pass ----------------
// blocks [0,8192): RoPE on Q,K from cf -> qbuf/kbuf (b,h,s,d), Q scaled 1/8.
// blocks [8192,9216): transpose V slice of cf (b,s,h,d) -> vt (b,h,d,s).
__global__ __launch_bounds__(256) void rope_tv(const unsigned short* __restrict__ cf,
                                               unsigned short* __restrict__ qb,
                                               unsigned short* __restrict__ kb,
                                               unsigned short* __restrict__ vt) {
  __shared__ unsigned short tile[64][72];
  const int bid = blockIdx.x;
  if (bid < 8192) {
    int i = bid * 256 + threadIdx.x;  // 2M pairs
    int k = i & 31, h = (i >> 5) & 15, s = (i >> 9) & 1023, b = i >> 19;
    float freq = __expf(-(float)k * 0.28782313662425572f);  // 10000^(-k/32)
    float ang = (float)s * freq;
    float sn, cs;
    __sincosf(ang, &sn, &cs);
    const unsigned short* src = cf + (size_t)(b * SEQ + s) * N3 + h * DKH + 2 * k;
    float qe = bf2f(src[0]), qo = bf2f(src[1]);
    float ke = bf2f(src[DM]), ko = bf2f(src[DM + 1]);
    float q0 = (qe * cs - qo * sn) * 0.125f;
    float q1 = (qe * sn + qo * cs) * 0.125f;
    float k0 = ke * cs - ko * sn;
    float k1 = ke * sn + ko * cs;
    size_t dsto = (size_t)((b * NH + h) * SEQ + s) * DKH + 2 * k;
    *(unsigned*)(qb + dsto) = cvt_pk_bf16(q0, q1);
    *(unsigned*)(kb + dsto) = cvt_pk_bf16(k0, k1);
  } else {
    int t = bid - 8192;
    int bh = t >> 4, b = bh >> 4, h = bh & 15, s0 = (t & 15) * 64;
    int tt = threadIdx.x, row = tt >> 2, c0 = (tt & 3) * 16;
    const unsigned short* src = cf + (size_t)(b * SEQ + s0 + row) * N3 + 2 * DM + h * DKH + c0;
    short8 v0 = *(const short8*)src;
    short8 v1 = *(const short8*)(src + 8);
    *(short8*)&tile[row][c0] = v0;
    *(short8*)&tile[row][c0 + 8] = v1;
    __syncthreads();
    unsigned short* dst = vt + ((size_t)bh * DKH + row) * SEQ + s0 + c0;
    short8 o0, o1;
#pragma unroll
    for (int j = 0; j < 8; ++j) o0[j] = (short)tile[c0 + j][row];
#pragma unroll
    for (int j = 0; j < 8; ++j) o1[j] = (short)tile[c0 + 8 + j][row];
    *(short8*)dst = o0;
    *(short8*)(dst + 8) = o1;
  }
}

// ---------------- causal flash attention (v4 + cvt_pk packing) ----------
// grid (8, 64), paired q-blocks (qlo=bx, qhi=15-bx). QK^T computed as mfma(K,Q)
// so S lands q-on-col: each lane owns ONE q-row -> per-lane softmax + 2 shfl.
// PV swapped: mfma(V^T, P) keeps q-on-col; m/l/rescale are per-lane scalars.
// P-store packing via v_cvt_pk_bf16_f32 (1 instr per f32 pair vs ~10 int-ops).
__global__ __launch_bounds__(256) void attn_kernel(const unsigned short* __restrict__ qb,
                                                   const unsigned short* __restrict__ kb,
                                                   const unsigned short* __restrict__ vt,
                                                   unsigned short* __restrict__ ob) {
  __shared__ char kl[2][8192];
  __shared__ char vl[2][8192];
  __shared__ unsigned short plds[4][2][1024];  // per-wave P buffers (hi, lo)
  const int bx = blockIdx.x, bh = blockIdx.y, b = bh >> 4, h = bh & 15;
  const int qlo = bx, qhi = 15 - bx;
  const int tid = threadIdx.x, w = tid >> 6, lane = tid & 63;
  const int g = lane >> 4, r = lane & 15;
  const unsigned short* Q = qb + (size_t)bh * SEQ * DKH;
  const char* Kp = (const char*)(kb + (size_t)bh * SEQ * DKH);
  const char* Vp = (const char*)(vt + (size_t)bh * DKH * SEQ);

  const int p0 = (w << 10) + lane * 16;
  const int p1 = p0 + 4096;
  const int o0 = p0 ^ (((p0 >> 7) & 7) << 4);
  const int o1 = p1 ^ (((p1 >> 7) & 7) << 4);
  const int r0 = o0 >> 7, c0 = o0 & 127, r1 = o1 >> 7, c1 = o1 & 127;
  const size_t ks0 = (size_t)r0 * 128 + c0, ks1 = (size_t)r1 * 128 + c1;
  const size_t vs0 = (size_t)r0 * 2048 + c0, vs1 = (size_t)r1 * 2048 + c1;

#define STAGE_KV(bi, kt)                                                          \
  do {                                                                            \
    const char* kbase = Kp + (size_t)(kt) * 8192;                                 \
    const char* vbase = Vp + (size_t)(kt) * 128;                                  \
    __builtin_amdgcn_global_load_lds((const AS1 void*)(kbase + ks0),              \
                                     (AS3 void*)(kl[bi] + p0), 16, 0, 0);         \
    __builtin_amdgcn_global_load_lds((const AS1 void*)(kbase + ks1),              \
                                     (AS3 void*)(kl[bi] + p1), 16, 0, 0);         \
    __builtin_amdgcn_global_load_lds((const AS1 void*)(vbase + vs0),              \
                                     (AS3 void*)(vl[bi] + p0), 16, 0, 0);         \
    __builtin_amdgcn_global_load_lds((const AS1 void*)(vbase + vs1),              \
                                     (AS3 void*)(vl[bi] + p1), 16, 0, 0);         \
  } while (0)

  short8 qfL0, qfL1, qfH0, qfH1;
  {
    int qrL = qlo * 64 + w * 16 + r;
    int qrH = qhi * 64 + w * 16 + r;
    qfL0 = *(const short8*)(Q + (size_t)qrL * DKH + g * 8);
    qfL1 = *(const short8*)(Q + (size_t)qrL * DKH + 32 + g * 8);
    qfH0 = *(const short8*)(Q + (size_t)qrH * DKH + g * 8);
    qfH1 = *(const short8*)(Q + (size_t)qrH * DKH + 32 + g * 8);
  }
  f32x4 oaccL[4] = {}, oaccH[4] = {};
  float mrunL = -1e30f, lrunL = 0.f, mrunH = -1e30f, lrunH = 0.f;
  const int qgH = qhi * 64 + w * 16 + r;
  const int qgL = qlo * 64 + w * 16 + r;
  char* pbH = (char*)&plds[w][0][0];
  char* pbL = (char*)&plds[w][1][0];

  STAGE_KV(0, 0);
  __syncthreads();

  for (int kt = 0; kt <= qhi; ++kt) {
    if (kt < qhi) STAGE_KV((kt + 1) & 1, kt + 1);
    const bool doLo = (kt <= qlo);
    const char* kb_ = kl[kt & 1];
    const char* vb_ = vl[kt & 1];
    f32x4 sh[4] = {}, sl[4] = {};
#pragma unroll
    for (int nb = 0; nb < 4; ++nb) {
      int ra = nb * 16 + r;
      short8 kf0 = *(const short8*)(kb_ + ((ra * 128 + g * 16) ^ ((ra & 7) << 4)));
      short8 kf1 = *(const short8*)(kb_ + ((ra * 128 + 64 + g * 16) ^ ((ra & 7) << 4)));
      sh[nb] = mfma16(kf0, qfH0, sh[nb]);
      sh[nb] = mfma16(kf1, qfH1, sh[nb]);
      if (doLo) {
        sl[nb] = mfma16(kf0, qfL0, sl[nb]);
        sl[nb] = mfma16(kf1, qfL1, sl[nb]);
      }
    }
    if (kt == qhi) {
#pragma unroll
      for (int nb = 0; nb < 4; ++nb)
#pragma unroll
        for (int j = 0; j < 4; ++j)
          if (kt * 64 + nb * 16 + g * 4 + j > qgH) sh[nb][j] = -1e30f;
    }
    if (kt == qlo) {
#pragma unroll
      for (int nb = 0; nb < 4; ++nb)
#pragma unroll
        for (int j = 0; j < 4; ++j)
          if (kt * 64 + nb * 16 + g * 4 + j > qgL) sl[nb][j] = -1e30f;
    }
    float sclH, sclL = 1.f;
    {
      float a0 = fmaxf(fmaxf(sh[0][0], sh[0][1]), fmaxf(sh[0][2], sh[0][3]));
      float a1 = fmaxf(fmaxf(sh[1][0], sh[1][1]), fmaxf(sh[1][2], sh[1][3]));
      float a2 = fmaxf(fmaxf(sh[2][0], sh[2][1]), fmaxf(sh[2][2], sh[2][3]));
      float a3 = fmaxf(fmaxf(sh[3][0], sh[3][1]), fmaxf(sh[3][2], sh[3][3]));
      float tm = fmaxf(fmaxf(a0, a1), fmaxf(a2, a3));
      tm = fmaxf(tm, __shfl_xor(tm, 16, 64));
      tm = fmaxf(tm, __shfl_xor(tm, 32, 64));
      float mnew = fmaxf(mrunH, tm);
      sclH = __expf(mrunH - mnew);
      mrunH = mnew;
      float ps = 0.f;
#pragma unroll
      for (int nb = 0; nb < 4; ++nb)
#pragma unroll
        for (int j = 0; j < 4; ++j) {
          float p = __expf(sh[nb][j] - mnew);
          sh[nb][j] = p;
          ps += p;
        }
      ps += __shfl_xor(ps, 16, 64);
      ps += __shfl_xor(ps, 32, 64);
      lrunH = lrunH * sclH + ps;
#pragma unroll
      for (int nb = 0; nb < 4; ++nb) {
        uint2v pk;
        pk.x = cvt_pk_bf16(sh[nb][0], sh[nb][1]);
        pk.y = cvt_pk_bf16(sh[nb][2], sh[nb][3]);
        *(uint2v*)(pbH + ((r * 128 + nb * 32 + g * 8) ^ ((r & 7) << 4))) = pk;
      }
    }
    if (doLo) {
      float a0 = fmaxf(fmaxf(sl[0][0], sl[0][1]), fmaxf(sl[0][2], sl[0][3]));
      float a1 = fmaxf(fmaxf(sl[1][0], sl[1][1]), fmaxf(sl[1][2], sl[1][3]));
      float a2 = fmaxf(fmaxf(sl[2][0], sl[2][1]), fmaxf(sl[2][2], sl[2][3]));
      float a3 = fmaxf(fmaxf(sl[3][0], sl[3][1]), fmaxf(sl[3][2], sl[3][3]));
      float tm = fmaxf(fmaxf(a0, a1), fmaxf(a2, a3));
      tm = fmaxf(tm, __shfl_xor(tm, 16, 64));
      tm = fmaxf(tm, __shfl_xor(tm, 32, 64));
      float mnew = fmaxf(mrunL, tm);
      sclL = __expf(mrunL - mnew);
      mrunL = mnew;
      float ps = 0.f;
#pragma unroll
      for (int nb = 0; nb < 4; ++nb)
#pragma unroll
        for (int j = 0; j < 4; ++j) {
          float p = __expf(sl[nb][j] - mnew);
          sl[nb][j] = p;
          ps += p;
        }
      ps += __shfl_xor(ps, 16, 64);
      ps += __shfl_xor(ps, 32, 64);
      lrunL = lrunL * sclL + ps;
#pragma unroll
      for (int nb = 0; nb < 4; ++nb) {
        uint2v pk;
        pk.x = cvt_pk_bf16(sl[nb][0], sl[nb][1]);
        pk.y = cvt_pk_bf16(sl[nb][2], sl[nb][3]);
        *(uint2v*)(pbL + ((r * 128 + nb * 32 + g * 8) ^ ((r & 7) << 4))) = pk;
      }
    }
#pragma unroll
    for (int db = 0; db < 4; ++db) {
      f32x4 t = oaccH[db];
      t[0] *= sclH; t[1] *= sclH; t[2] *= sclH; t[3] *= sclH;
      oaccH[db] = t;
      if (doLo) {
        f32x4 u = oaccL[db];
        u[0] *= sclL; u[1] *= sclL; u[2] *= sclL; u[3] *= sclL;
        oaccL[db] = u;
      }
    }
    asm volatile("s_waitcnt lgkmcnt(0)" ::: "memory");
    __builtin_amdgcn_sched_barrier(0);
    short8 pfH0 = *(const short8*)(pbH + ((r * 128 + g * 16) ^ ((r & 7) << 4)));
    short8 pfH1 = *(const short8*)(pbH + ((r * 128 + 64 + g * 16) ^ ((r & 7) << 4)));
    short8 pfL0, pfL1;
    if (doLo) {
      pfL0 = *(const short8*)(pbL + ((r * 128 + g * 16) ^ ((r & 7) << 4)));
      pfL1 = *(const short8*)(pbL + ((r * 128 + 64 + g * 16) ^ ((r & 7) << 4)));
    }
#pragma unroll
    for (int db = 0; db < 4; ++db) {
      int rv = db * 16 + r;
      short8 vf0 = *(const short8*)(vb_ + ((rv * 128 + g * 16) ^ ((rv & 7) << 4)));
      short8 vf1 = *(const short8*)(vb_ + ((rv * 128 + 64 + g * 16) ^ ((rv & 7) << 4)));
      oaccH[db] = mfma16(vf0, pfH0, oaccH[db]);
      oaccH[db] = mfma16(vf1, pfH1, oaccH[db]);
      if (doLo) {
        oaccL[db] = mfma16(vf0, pfL0, oaccL[db]);
        oaccL[db] = mfma16(vf1, pfL1, oaccL[db]);
      }
    }
    __syncthreads();
  }
  {
    float invH = 1.f / lrunH;
    unsigned short* orH = ob + (size_t)(b * SEQ + qgH) * DM + h * DKH;
#pragma unroll
    for (int db = 0; db < 4; ++db) {
      uint2v pk;
      pk.x = cvt_pk_bf16(oaccH[db][0] * invH, oaccH[db][1] * invH);
      pk.y = cvt_pk_bf16(oaccH[db][2] * invH, oaccH[db][3] * invH);
      *(uint2v*)(orH + db * 16 + g * 4) = pk;
    }
    float invL = 1.f / lrunL;
    unsigned short* orL = ob + (size_t)(b * SEQ + qgL) * DM + h * DKH;
#pragma unroll
    for (int db = 0; db < 4; ++db) {
      uint2v pk;
      pk.x = cvt_pk_bf16(oaccL[db][0] * invL, oaccL[db][1] * invL);
      pk.y = cvt_pk_bf16(oaccL[db][2] * invL, oaccL[db][3] * invL);
      *(uint2v*)(orL + db * 16 + g * 4) = pk;
    }
  }
#undef STAGE_KV
}

extern "C" void kernel_launch(void* const* d_in, const int* in_sizes, int n_in,
                              void* d_out, int out_size, void* d_ws, size_t ws_size,
                              hipStream_t stream) {
  const float* x = (const float*)d_in[0];
  // d_in[1] = token_positions (reference ignores it; positions == arange(S))
  const float* wq = (const float*)d_in[2];
  const float* wk = (const float*)d_in[3];
  const float* wv = (const float*)d_in[4];
  const float* wo = (const float*)d_in[5];
  char* ws = (char*)d_ws;
  unsigned short* xb = (unsigned short*)(ws);                  // 8 MiB
  unsigned short* wqkv = (unsigned short*)(ws + (8u << 20));   // 6 MiB [Wq;Wk;Wv][3072][1024]
  unsigned short* wob = (unsigned short*)(ws + (14u << 20));   // 2 MiB
  unsigned short* cf = (unsigned short*)(ws + (16u << 20));    // 24 MiB QKV gemm out (b,s,3072)
  unsigned short* qbuf = (unsigned short*)(ws + (40u << 20));  // 8 MiB (bh,s,d)
  unsigned short* kbuf = (unsigned short*)(ws + (48u << 20));  // 8 MiB (bh,s,d)
  unsigned short* vtb = (unsigned short*)(ws + (56u << 20));   // 8 MiB (bh,d,s)
  unsigned short* obuf = (unsigned short*)(ws + (64u << 20));  // 8 MiB (b,s,e)
  float* out = (float*)d_out;

  convert_kernel<<<8192, 256, 0, stream>>>(x, wq, wk, wv, wo, xb, wqkv, wob);
  gemm_bt<unsigned short><<<dim3(24, 32), 256, 0, stream>>>(xb, wqkv, cf, MROWS, N3, DM);
  rope_tv<<<9216, 256, 0, stream>>>(cf, qbuf, kbuf, vtb);
  attn_kernel<<<dim3(8, 64), 256, 0, stream>>>(qbuf, kbuf, vtb, obuf);
  gemm_bt<float><<<dim3(8, 32), 256, 0, stream>>>(obuf, wob, out, MROWS, DM, DM);
}

// Round 11
// 105.430 us; speedup vs baseline: 1.8248x; 1.0729x over previous
//
#include <hip/hip_runtime.h>

typedef __attribute__((ext_vector_type(8))) short short8;
typedef __attribute__((ext_vector_type(8))) __bf16 bf16x8;
typedef __attribute__((ext_vector_type(4))) float f32x4;
typedef __attribute__((ext_vector_type(4))) float float4v;
typedef __attribute__((ext_vector_type(4))) unsigned short ushort4v;
typedef __attribute__((ext_vector_type(2))) unsigned uint2v;
typedef __attribute__((ext_vector_type(4))) unsigned uint4v;

#define AS1 __attribute__((address_space(1)))
#define AS3 __attribute__((address_space(3)))

#define BATCH 4
#define SEQ 1024
#define DM 1024
#define NH 16
#define DKH 64
#define MROWS (BATCH * SEQ) /* 4096 */
#define N3 (3 * DM)         /* 3072 */

static __device__ __forceinline__ unsigned short f2bf(float f) {
  unsigned u = __builtin_bit_cast(unsigned, f);
  u += 0x7FFFu + ((u >> 16) & 1u);
  return (unsigned short)(u >> 16);
}
static __device__ __forceinline__ float bf2f(unsigned short h) {
  return __builtin_bit_cast(float, ((unsigned)h) << 16);
}
// HW packed f32x2 -> bf16x2 (RTNE)
static __device__ __forceinline__ unsigned cvt_pk_bf16(float lo, float hi) {
  unsigned r;
  asm("v_cvt_pk_bf16_f32 %0, %1, %2" : "=v"(r) : "v"(lo), "v"(hi));
  return r;
}
static __device__ __forceinline__ f32x4 mfma16(short8 a, short8 b, f32x4 c) {
  return __builtin_amdgcn_mfma_f32_16x16x32_bf16(
      __builtin_bit_cast(bf16x8, a), __builtin_bit_cast(bf16x8, b), c, 0, 0, 0);
}

// ---------------- fp32 -> bf16 convert (x, Wq, Wk, Wv concat, Wo) ----------------
__global__ __launch_bounds__(256) void convert_kernel(
    const float* __restrict__ x, const float* __restrict__ wq,
    const float* __restrict__ wk, const float* __restrict__ wv,
    const float* __restrict__ wo, unsigned short* __restrict__ xb,
    unsigned short* __restrict__ wqkv, unsigned short* __restrict__ wob) {
  size_t i4 = ((size_t)blockIdx.x * 256 + threadIdx.x) * 4;
  const size_t SZX = (size_t)MROWS * DM;  // 4M
  const size_t SZW = (size_t)DM * DM;     // 1M
  const float* src;
  unsigned short* dst;
  size_t off;
  if (i4 < SZX) {
    src = x; dst = xb; off = i4;
  } else if (i4 < SZX + SZW) {
    src = wq; dst = wqkv; off = i4 - SZX;
  } else if (i4 < SZX + 2 * SZW) {
    src = wk; dst = wqkv + SZW; off = i4 - SZX - SZW;
  } else if (i4 < SZX + 3 * SZW) {
    src = wv; dst = wqkv + 2 * SZW; off = i4 - SZX - 2 * SZW;
  } else {
    src = wo; dst = wob; off = i4 - SZX - 3 * SZW;
  }
  float4v v = *(const float4v*)(src + off);
  uint2v o;
  o.x = cvt_pk_bf16(v.x, v.y);
  o.y = cvt_pk_bf16(v.z, v.w);
  *(uint2v*)(dst + off) = o;
}

// ---------------- bf16 GEMM: C[M][N] = A[M][K] * B[N][K]^T ----------------
// 128x128 tile, BK=64, 4 waves (2x2 of 64x64), global_load_lds + XOR swizzle.
static __device__ __forceinline__ void store_c(float* p, float v) { *p = v; }
static __device__ __forceinline__ void store_c(unsigned short* p, float v) { *p = f2bf(v); }

template <typename OutT>
__global__ __launch_bounds__(256) void gemm_bt(
    const unsigned short* __restrict__ A, const unsigned short* __restrict__ B,
    OutT* __restrict__ C, int M, int N, int K) {
  __shared__ char sA[16384];
  __shared__ char sB[16384];
  const int tid = threadIdx.x, w = tid >> 6, lane = tid & 63;
  const int g = lane >> 4, r = lane & 15;
  const int m0 = blockIdx.y * 128, n0 = blockIdx.x * 128;
  const int wm = (w >> 1) * 64, wn = (w & 1) * 64;
  f32x4 acc[4][4] = {};
  for (int k0 = 0; k0 < K; k0 += 64) {
#pragma unroll
    for (int c = 0; c < 4; ++c) {
      int p = c * 4096 + tid * 16;            // linear LDS byte pos
      int o = p ^ (((p >> 7) & 7) << 4);      // inverse-swizzled logical pos
      int row = o >> 7, colb = o & 127;
      const char* ga = (const char*)(A + (size_t)(m0 + row) * K + k0) + colb;
      const char* gb = (const char*)(B + (size_t)(n0 + row) * K + k0) + colb;
      __builtin_amdgcn_global_load_lds((const AS1 void*)ga,
                                       (AS3 void*)(sA + c * 4096 + (w << 10)), 16, 0, 0);
      __builtin_amdgcn_global_load_lds((const AS1 void*)gb,
                                       (AS3 void*)(sB + c * 4096 + (w << 10)), 16, 0, 0);
    }
    __syncthreads();
#pragma unroll
    for (int kk = 0; kk < 2; ++kk) {
      short8 af[4], bfr[4];
#pragma unroll
      for (int i = 0; i < 4; ++i) {
        int ra = wm + i * 16 + r;
        af[i] = *(const short8*)(sA + (((ra << 7) + (kk << 6) + (g << 4)) ^ ((ra & 7) << 4)));
        int rb = wn + i * 16 + r;
        bfr[i] = *(const short8*)(sB + (((rb << 7) + (kk << 6) + (g << 4)) ^ ((rb & 7) << 4)));
      }
#pragma unroll
      for (int i = 0; i < 4; ++i)
#pragma unroll
        for (int j = 0; j < 4; ++j) acc[i][j] = mfma16(af[i], bfr[j], acc[i][j]);
    }
    __syncthreads();
  }
#pragma unroll
  for (int i = 0; i < 4; ++i)
#pragma unroll
    for (int j = 0; j < 4; ++j)
#pragma unroll
      for (int jj = 0; jj < 4; ++jj) {
        int row = m0 + wm + i * 16 + g * 4 + jj;
        int col = n0 + wn + j * 16 + r;
        store_c(&C[(size_t)row * N + col], acc[i][j][jj]);
      }
}

// ---------------- 128x64-tile GEMM (for N=1024 out-proj: 2 blocks/CU) ----------
// 4 waves as 2x2 of 64x32; same staging/swizzle pattern, B-tile = 8KB (2 chunks).
__global__ __launch_bounds__(256) void gemm_n64(
    const unsigned short* __restrict__ A, const unsigned short* __restrict__ B,
    float* __restrict__ C, int M, int N, int K) {
  __shared__ char sA[16384];
  __shared__ char sB[8192];
  const int tid = threadIdx.x, w = tid >> 6, lane = tid & 63;
  const int g = lane >> 4, r = lane & 15;
  const int m0 = blockIdx.y * 128, n0 = blockIdx.x * 64;
  const int wm = (w >> 1) * 64, wn = (w & 1) * 32;
  f32x4 acc[4][2] = {};
  for (int k0 = 0; k0 < K; k0 += 64) {
#pragma unroll
    for (int c = 0; c < 4; ++c) {
      int p = c * 4096 + tid * 16;
      int o = p ^ (((p >> 7) & 7) << 4);
      int row = o >> 7, colb = o & 127;
      const char* ga = (const char*)(A + (size_t)(m0 + row) * K + k0) + colb;
      __builtin_amdgcn_global_load_lds((const AS1 void*)ga,
                                       (AS3 void*)(sA + c * 4096 + (w << 10)), 16, 0, 0);
      if (c < 2) {
        const char* gb = (const char*)(B + (size_t)(n0 + row) * K + k0) + colb;
        __builtin_amdgcn_global_load_lds((const AS1 void*)gb,
                                         (AS3 void*)(sB + c * 4096 + (w << 10)), 16, 0, 0);
      }
    }
    __syncthreads();
#pragma unroll
    for (int kk = 0; kk < 2; ++kk) {
      short8 af[4], bfr[2];
#pragma unroll
      for (int i = 0; i < 4; ++i) {
        int ra = wm + i * 16 + r;
        af[i] = *(const short8*)(sA + (((ra << 7) + (kk << 6) + (g << 4)) ^ ((ra & 7) << 4)));
      }
#pragma unroll
      for (int j = 0; j < 2; ++j) {
        int rb = wn + j * 16 + r;
        bfr[j] = *(const short8*)(sB + (((rb << 7) + (kk << 6) + (g << 4)) ^ ((rb & 7) << 4)));
      }
#pragma unroll
      for (int i = 0; i < 4; ++i)
#pragma unroll
        for (int j = 0; j < 2; ++j) acc[i][j] = mfma16(af[i], bfr[j], acc[i][j]);
    }
    __syncthreads();
  }
#pragma unroll
  for (int i = 0; i < 4; ++i)
#pragma unroll
    for (int j = 0; j < 2; ++j)
#pragma unroll
      for (int jj = 0; jj < 4; ++jj) {
        int row = m0 + wm + i * 16 + g * 4 + jj;
        int col = n0 + wn + j * 16 + r;
        C[(size_t)row * N + col] = acc[i][j][jj];
      }
}

// ---------------- fused RoPE(Q,K) (vectorized, 4 pairs/thread) + V-transpose ----
// blocks [0,2048): thread handles 8 dims (4 RoPE pairs) of one (b,s,h):
//   16B loads from cf Q and K slices, 16B stores to qbuf/kbuf. Q scaled 1/8.
// blocks [2048,3072): transpose V slice of cf (b,s,h,d) -> vt (b,h,d,s).
__global__ __launch_bounds__(256) void rope_tv(const unsigned short* __restrict__ cf,
                                               unsigned short* __restrict__ qb,
                                               unsigned short* __restrict__ kb,
                                               unsigned short* __restrict__ vt) {
  __shared__ unsigned short tile[64][72];
  const int bid = blockIdx.x;
  if (bid < 2048) {
    int i = bid * 256 + threadIdx.x;  // 512K threads: ((b*1024+s)*16+h)*8+t8
    int t8 = i & 7, h = (i >> 3) & 15, s = (i >> 7) & 1023, b = i >> 17;
    const unsigned short* src = cf + (size_t)(b * SEQ + s) * N3 + h * DKH + t8 * 8;
    short8 q8 = *(const short8*)src;
    short8 k8 = *(const short8*)(src + DM);
    uint4v qo, ko;
#pragma unroll
    for (int p = 0; p < 4; ++p) {
      int kidx = t8 * 4 + p;
      float freq = __expf(-(float)kidx * 0.28782313662425572f);  // 10000^(-k/32)
      float sn, cs;
      __sincosf((float)s * freq, &sn, &cs);
      float qe = bf2f((unsigned short)q8[2 * p]), qv = bf2f((unsigned short)q8[2 * p + 1]);
      float ke = bf2f((unsigned short)k8[2 * p]), kv = bf2f((unsigned short)k8[2 * p + 1]);
      qo[p] = cvt_pk_bf16((qe * cs - qv * sn) * 0.125f, (qe * sn + qv * cs) * 0.125f);
      ko[p] = cvt_pk_bf16(ke * cs - kv * sn, ke * sn + kv * cs);
    }
    size_t dsto = (size_t)((b * NH + h) * SEQ + s) * DKH + t8 * 8;
    *(uint4v*)(qb + dsto) = qo;
    *(uint4v*)(kb + dsto) = ko;
  } else {
    int t = bid - 2048;
    int bh = t >> 4, b = bh >> 4, h = bh & 15, s0 = (t & 15) * 64;
    int tt = threadIdx.x, row = tt >> 2, c0 = (tt & 3) * 16;
    const unsigned short* src = cf + (size_t)(b * SEQ + s0 + row) * N3 + 2 * DM + h * DKH + c0;
    short8 v0 = *(const short8*)src;
    short8 v1 = *(const short8*)(src + 8);
    *(short8*)&tile[row][c0] = v0;
    *(short8*)&tile[row][c0 + 8] = v1;
    __syncthreads();
    unsigned short* dst = vt + ((size_t)bh * DKH + row) * SEQ + s0 + c0;
    short8 o0, o1;
#pragma unroll
    for (int j = 0; j < 8; ++j) o0[j] = (short)tile[c0 + j][row];
#pragma unroll
    for (int j = 0; j < 8; ++j) o1[j] = (short)tile[c0 + 8 + j][row];
    *(short8*)dst = o0;
    *(short8*)(dst + 8) = o1;
  }
}

// ---------------- causal flash attention (v4 + cvt_pk + defer-max T13) ----------
// grid (8, 64), paired q-blocks (qlo=bx, qhi=15-bx). Swapped-operand: per-lane
// softmax, q-on-col. Defer-max: skip exp+O-rescale when tile max <= m_run+8
// (wave-uniform branch; P bounded by e^8, f32 l-accum tolerates).
__global__ __launch_bounds__(256) void attn_kernel(const unsigned short* __restrict__ qb,
                                                   const unsigned short* __restrict__ kb,
                                                   const unsigned short* __restrict__ vt,
                                                   unsigned short* __restrict__ ob) {
  __shared__ char kl[2][8192];
  __shared__ char vl[2][8192];
  __shared__ unsigned short plds[4][2][1024];  // per-wave P buffers (hi, lo)
  const int bx = blockIdx.x, bh = blockIdx.y, b = bh >> 4, h = bh & 15;
  const int qlo = bx, qhi = 15 - bx;
  const int tid = threadIdx.x, w = tid >> 6, lane = tid & 63;
  const int g = lane >> 4, r = lane & 15;
  const unsigned short* Q = qb + (size_t)bh * SEQ * DKH;
  const char* Kp = (const char*)(kb + (size_t)bh * SEQ * DKH);
  const char* Vp = (const char*)(vt + (size_t)bh * DKH * SEQ);

  const int p0 = (w << 10) + lane * 16;
  const int p1 = p0 + 4096;
  const int o0 = p0 ^ (((p0 >> 7) & 7) << 4);
  const int o1 = p1 ^ (((p1 >> 7) & 7) << 4);
  const int r0 = o0 >> 7, c0 = o0 & 127, r1 = o1 >> 7, c1 = o1 & 127;
  const size_t ks0 = (size_t)r0 * 128 + c0, ks1 = (size_t)r1 * 128 + c1;
  const size_t vs0 = (size_t)r0 * 2048 + c0, vs1 = (size_t)r1 * 2048 + c1;

#define STAGE_KV(bi, kt)                                                          \
  do {                                                                            \
    const char* kbase = Kp + (size_t)(kt) * 8192;                                 \
    const char* vbase = Vp + (size_t)(kt) * 128;                                  \
    __builtin_amdgcn_global_load_lds((const AS1 void*)(kbase + ks0),              \
                                     (AS3 void*)(kl[bi] + p0), 16, 0, 0);         \
    __builtin_amdgcn_global_load_lds((const AS1 void*)(kbase + ks1),              \
                                     (AS3 void*)(kl[bi] + p1), 16, 0, 0);         \
    __builtin_amdgcn_global_load_lds((const AS1 void*)(vbase + vs0),              \
                                     (AS3 void*)(vl[bi] + p0), 16, 0, 0);         \
    __builtin_amdgcn_global_load_lds((const AS1 void*)(vbase + vs1),              \
                                     (AS3 void*)(vl[bi] + p1), 16, 0, 0);         \
  } while (0)

  short8 qfL0, qfL1, qfH0, qfH1;
  {
    int qrL = qlo * 64 + w * 16 + r;
    int qrH = qhi * 64 + w * 16 + r;
    qfL0 = *(const short8*)(Q + (size_t)qrL * DKH + g * 8);
    qfL1 = *(const short8*)(Q + (size_t)qrL * DKH + 32 + g * 8);
    qfH0 = *(const short8*)(Q + (size_t)qrH * DKH + g * 8);
    qfH1 = *(const short8*)(Q + (size_t)qrH * DKH + 32 + g * 8);
  }
  f32x4 oaccL[4] = {}, oaccH[4] = {};
  float mrunL = -1e30f, lrunL = 0.f, mrunH = -1e30f, lrunH = 0.f;
  const int qgH = qhi * 64 + w * 16 + r;
  const int qgL = qlo * 64 + w * 16 + r;
  char* pbH = (char*)&plds[w][0][0];
  char* pbL = (char*)&plds[w][1][0];

  STAGE_KV(0, 0);
  __syncthreads();

  for (int kt = 0; kt <= qhi; ++kt) {
    if (kt < qhi) STAGE_KV((kt + 1) & 1, kt + 1);
    const bool doLo = (kt <= qlo);
    const char* kb_ = kl[kt & 1];
    const char* vb_ = vl[kt & 1];
    f32x4 sh[4] = {}, sl[4] = {};
#pragma unroll
    for (int nb = 0; nb < 4; ++nb) {
      int ra = nb * 16 + r;
      short8 kf0 = *(const short8*)(kb_ + ((ra * 128 + g * 16) ^ ((ra & 7) << 4)));
      short8 kf1 = *(const short8*)(kb_ + ((ra * 128 + 64 + g * 16) ^ ((ra & 7) << 4)));
      sh[nb] = mfma16(kf0, qfH0, sh[nb]);
      sh[nb] = mfma16(kf1, qfH1, sh[nb]);
      if (doLo) {
        sl[nb] = mfma16(kf0, qfL0, sl[nb]);
        sl[nb] = mfma16(kf1, qfL1, sl[nb]);
      }
    }
    if (kt == qhi) {
#pragma unroll
      for (int nb = 0; nb < 4; ++nb)
#pragma unroll
        for (int j = 0; j < 4; ++j)
          if (kt * 64 + nb * 16 + g * 4 + j > qgH) sh[nb][j] = -1e30f;
    }
    if (kt == qlo) {
#pragma unroll
      for (int nb = 0; nb < 4; ++nb)
#pragma unroll
        for (int j = 0; j < 4; ++j)
          if (kt * 64 + nb * 16 + g * 4 + j > qgL) sl[nb][j] = -1e30f;
    }
    // ---- softmax H (per-lane row; defer-max) ----
    {
      float a0 = fmaxf(fmaxf(sh[0][0], sh[0][1]), fmaxf(sh[0][2], sh[0][3]));
      float a1 = fmaxf(fmaxf(sh[1][0], sh[1][1]), fmaxf(sh[1][2], sh[1][3]));
      float a2 = fmaxf(fmaxf(sh[2][0], sh[2][1]), fmaxf(sh[2][2], sh[2][3]));
      float a3 = fmaxf(fmaxf(sh[3][0], sh[3][1]), fmaxf(sh[3][2], sh[3][3]));
      float tm = fmaxf(fmaxf(a0, a1), fmaxf(a2, a3));
      tm = fmaxf(tm, __shfl_xor(tm, 16, 64));
      tm = fmaxf(tm, __shfl_xor(tm, 32, 64));
      if (!__all(tm <= mrunH + 8.f)) {  // rescale only when max grew (T13)
        float mnew = fmaxf(mrunH, tm);
        float scl = __expf(mrunH - mnew);
        mrunH = mnew;
        lrunH *= scl;
#pragma unroll
        for (int db = 0; db < 4; ++db) {
          f32x4 t = oaccH[db];
          t[0] *= scl; t[1] *= scl; t[2] *= scl; t[3] *= scl;
          oaccH[db] = t;
        }
      }
      float ps = 0.f;
#pragma unroll
      for (int nb = 0; nb < 4; ++nb)
#pragma unroll
        for (int j = 0; j < 4; ++j) {
          float p = __expf(sh[nb][j] - mrunH);
          sh[nb][j] = p;
          ps += p;
        }
      ps += __shfl_xor(ps, 16, 64);
      ps += __shfl_xor(ps, 32, 64);
      lrunH += ps;
#pragma unroll
      for (int nb = 0; nb < 4; ++nb) {
        uint2v pk;
        pk.x = cvt_pk_bf16(sh[nb][0], sh[nb][1]);
        pk.y = cvt_pk_bf16(sh[nb][2], sh[nb][3]);
        *(uint2v*)(pbH + ((r * 128 + nb * 32 + g * 8) ^ ((r & 7) << 4))) = pk;
      }
    }
    // ---- softmax L ----
    if (doLo) {
      float a0 = fmaxf(fmaxf(sl[0][0], sl[0][1]), fmaxf(sl[0][2], sl[0][3]));
      float a1 = fmaxf(fmaxf(sl[1][0], sl[1][1]), fmaxf(sl[1][2], sl[1][3]));
      float a2 = fmaxf(fmaxf(sl[2][0], sl[2][1]), fmaxf(sl[2][2], sl[2][3]));
      float a3 = fmaxf(fmaxf(sl[3][0], sl[3][1]), fmaxf(sl[3][2], sl[3][3]));
      float tm = fmaxf(fmaxf(a0, a1), fmaxf(a2, a3));
      tm = fmaxf(tm, __shfl_xor(tm, 16, 64));
      tm = fmaxf(tm, __shfl_xor(tm, 32, 64));
      if (!__all(tm <= mrunL + 8.f)) {
        float mnew = fmaxf(mrunL, tm);
        float scl = __expf(mrunL - mnew);
        mrunL = mnew;
        lrunL *= scl;
#pragma unroll
        for (int db = 0; db < 4; ++db) {
          f32x4 t = oaccL[db];
          t[0] *= scl; t[1] *= scl; t[2] *= scl; t[3] *= scl;
          oaccL[db] = t;
        }
      }
      float ps = 0.f;
#pragma unroll
      for (int nb = 0; nb < 4; ++nb)
#pragma unroll
        for (int j = 0; j < 4; ++j) {
          float p = __expf(sl[nb][j] - mrunL);
          sl[nb][j] = p;
          ps += p;
        }
      ps += __shfl_xor(ps, 16, 64);
      ps += __shfl_xor(ps, 32, 64);
      lrunL += ps;
#pragma unroll
      for (int nb = 0; nb < 4; ++nb) {
        uint2v pk;
        pk.x = cvt_pk_bf16(sl[nb][0], sl[nb][1]);
        pk.y = cvt_pk_bf16(sl[nb][2], sl[nb][3]);
        *(uint2v*)(pbL + ((r * 128 + nb * 32 + g * 8) ^ ((r & 7) << 4))) = pk;
      }
    }
    asm volatile("s_waitcnt lgkmcnt(0)" ::: "memory");
    __builtin_amdgcn_sched_barrier(0);
    short8 pfH0 = *(const short8*)(pbH + ((r * 128 + g * 16) ^ ((r & 7) << 4)));
    short8 pfH1 = *(const short8*)(pbH + ((r * 128 + 64 + g * 16) ^ ((r & 7) << 4)));
    short8 pfL0, pfL1;
    if (doLo) {
      pfL0 = *(const short8*)(pbL + ((r * 128 + g * 16) ^ ((r & 7) << 4)));
      pfL1 = *(const short8*)(pbL + ((r * 128 + 64 + g * 16) ^ ((r & 7) << 4)));
    }
#pragma unroll
    for (int db = 0; db < 4; ++db) {
      int rv = db * 16 + r;
      short8 vf0 = *(const short8*)(vb_ + ((rv * 128 + g * 16) ^ ((rv & 7) << 4)));
      short8 vf1 = *(const short8*)(vb_ + ((rv * 128 + 64 + g * 16) ^ ((rv & 7) << 4)));
      oaccH[db] = mfma16(vf0, pfH0, oaccH[db]);
      oaccH[db] = mfma16(vf1, pfH1, oaccH[db]);
      if (doLo) {
        oaccL[db] = mfma16(vf0, pfL0, oaccL[db]);
        oaccL[db] = mfma16(vf1, pfL1, oaccL[db]);
      }
    }
    __syncthreads();
  }
  {
    float invH = 1.f / lrunH;
    unsigned short* orH = ob + (size_t)(b * SEQ + qgH) * DM + h * DKH;
#pragma unroll
    for (int db = 0; db < 4; ++db) {
      uint2v pk;
      pk.x = cvt_pk_bf16(oaccH[db][0] * invH, oaccH[db][1] * invH);
      pk.y = cvt_pk_bf16(oaccH[db][2] * invH, oaccH[db][3] * invH);
      *(uint2v*)(orH + db * 16 + g * 4) = pk;
    }
    float invL = 1.f / lrunL;
    unsigned short* orL = ob + (size_t)(b * SEQ + qgL) * DM + h * DKH;
#pragma unroll
    for (int db = 0; db < 4; ++db) {
      uint2v pk;
      pk.x = cvt_pk_bf16(oaccL[db][0] * invL, oaccL[db][1] * invL);
      pk.y = cvt_pk_bf16(oaccL[db][2] * invL, oaccL[db][3] * invL);
      *(uint2v*)(orL + db * 16 + g * 4) = pk;
    }
  }
#undef STAGE_KV
}

extern "C" void kernel_launch(void* const* d_in, const int* in_sizes, int n_in,
                              void* d_out, int out_size, void* d_ws, size_t ws_size,
                              hipStream_t stream) {
  const float* x = (const float*)d_in[0];
  // d_in[1] = token_positions (reference ignores it; positions == arange(S))
  const float* wq = (const float*)d_in[2];
  const float* wk = (const float*)d_in[3];
  const float* wv = (const float*)d_in[4];
  const float* wo = (const float*)d_in[5];
  char* ws = (char*)d_ws;
  unsigned short* xb = (unsigned short*)(ws);                  // 8 MiB
  unsigned short* wqkv = (unsigned short*)(ws + (8u << 20));   // 6 MiB [Wq;Wk;Wv][3072][1024]
  unsigned short* wob = (unsigned short*)(ws + (14u << 20));   // 2 MiB
  unsigned short* cf = (unsigned short*)(ws + (16u << 20));    // 24 MiB QKV gemm out (b,s,3072)
  unsigned short* qbuf = (unsigned short*)(ws + (40u << 20));  // 8 MiB (bh,s,d)
  unsigned short* kbuf = (unsigned short*)(ws + (48u << 20));  // 8 MiB (bh,s,d)
  unsigned short* vtb = (unsigned short*)(ws + (56u << 20));   // 8 MiB (bh,d,s)
  unsigned short* obuf = (unsigned short*)(ws + (64u << 20));  // 8 MiB (b,s,e)
  float* out = (float*)d_out;

  convert_kernel<<<8192, 256, 0, stream>>>(x, wq, wk, wv, wo, xb, wqkv, wob);
  gemm_bt<unsigned short><<<dim3(24, 32), 256, 0, stream>>>(xb, wqkv, cf, MROWS, N3, DM);
  rope_tv<<<3072, 256, 0, stream>>>(cf, qbuf, kbuf, vtb);
  attn_kernel<<<dim3(8, 64), 256, 0, stream>>>(qbuf, kbuf, vtb, obuf);
  gemm_n64<<<dim3(16, 32), 256, 0, stream>>>(obuf, wob, out, MROWS, DM, DM);
}